// Round 12
// baseline (689.121 us; speedup 1.0000x reference)
//
#include <hip/hip_runtime.h>

// ---------------------------------------------------------------------------
// RowLSTM on MI355X — round 18: DEDICATED out waves (12-wave rnn block).
//  - R13/R14/R17 triangulated the law: all 10 waves are cell waves (no
//    spectators); convoy time = max per-wave added work. ANY 16-tile spread
//    on cell waves costs >=+24us. So add 2 waves that are NOT cell waves:
//    block = 768 thr. Waves 0-9 = byte-identical R8 cell structure (209us,
//    verified x3). Waves 10/11 = out waves: in window-0 of row t they read
//    row t-1's h from hC (intact until l6 — R13's invariant), compute 8
//    o-tiles each (2 ds_read_b128 + 16 MFMA + 32 stores) into ~97%-idle
//    pipes, then ride the barrier chain. Epilogue emits row 63.
// Carried: R16 channel-block conv + merged prep (2 dispatches), prefolded
// w_out/b_out tiles (bias via h[40]=1), R8 folded layer-0 + c' flag
// handshake, STP=56, packed 64-bit halo atomics, single end-of-row barrier,
// x double-buffer in regs, exp2-prescaled weights/x, lgkm-only barriers.
// ---------------------------------------------------------------------------

typedef __bf16 bf16x8 __attribute__((ext_vector_type(8)));
typedef __bf16 bf16x4 __attribute__((ext_vector_type(4)));
typedef float  f32x4  __attribute__((ext_vector_type(4)));

#define SC1 (-1.44269504089f)   // -log2(e)
#define SC2 (-2.88539008178f)   // -2 log2(e)

#define STP 56                   // bf16 elems per state column
#define HLS 896                  // hL per-buffer stride = 16*STP
#define CWS 17                   // cwf leading stride

#define BARRIER_LGKM() __asm__ volatile("s_waitcnt lgkmcnt(0)\ns_barrier" ::: "memory")

// ---------------------------------------------------------------------------
// Merged conv7 + prep dispatch: 908 blocks x 512 threads.
//  bid 0..639  : conv role, b = bid/40, cc = bid%40; wave wv rows 8wv..8wv+7.
//  bid 640..907: prep element i = (bid-640)*512+tid  (137216 total)
// wsA (bf16 elems):
//  [0     ,35840)  cell a0 : [(l*10+mt)][lane][j]  (l=0 part unused)
//  [35840 ,71680)  cell a1x: k<40 weight, k==40 bias, else 0
//  [71680 ,80896)  conv a0 : [(cv*9+dx*3+mtc)][lane][j] (cv=1 used)
//  [80896 ,90112)  conv a1x
//  [90112 ,105472) F a0  : F_dx = A0·Wrh_dx, scaled
//  [105472,120832) F a1x : k==40&&dx==1 -> s·(A0·b_rh + b_cell0)
//  [120832,129024) out a0 : [ot][lane][j]  o=ot*16+(lane&15), k=0..31, w_out
//  [129024,137216) out a1x: k=32..47; k<40 w_out, k==40 b_out, else 0
// x_ws (float, PRE-SCALED): [b][t][g4][mt10][q4][l16][gate4]
__global__ __launch_bounds__(512) void convprep_kernel(
        const float* __restrict__ inp, const float* __restrict__ tgt,
        const float* __restrict__ w_is, const float* __restrict__ b_is,
        const float* __restrict__ w_cis, const float* __restrict__ b_cis,
        const float* __restrict__ wcell, const float* __restrict__ wrh,
        const float* __restrict__ wrc, const float* __restrict__ bcell,
        const float* __restrict__ brh, const float* __restrict__ brc,
        const float* __restrict__ w_out, const float* __restrict__ b_out,
        float* __restrict__ x_ws, __bf16* __restrict__ wsA) {
    const int bidx = blockIdx.x;
    const int tid = threadIdx.x;
    if (bidx >= 640) {
        // ================= prep role =================
        int i = (bidx - 640) * 512 + tid;
        if (i >= 137216) return;
        float val = 0.0f;
        if (i < 35840) {                       // cell a0
            int j = i & 7, lane = (i >> 3) & 63, lm = i >> 9;
            int mt = lm % 10, l = lm / 10;
            int k = (lane >> 4) * 8 + j, m = lane & 15, r = m & 3;
            int row = r * 40 + 4 * mt + (m >> 2);
            val = wcell[(l * 160 + row) * 40 + k] * (r == 3 ? SC2 : SC1);
        } else if (i < 71680) {                // cell a1 ext
            int i2 = i - 35840;
            int j = i2 & 7, lane = (i2 >> 3) & 63, lm = i2 >> 9;
            int mt = lm % 10, l = lm / 10;
            int k = 32 + (lane >> 4) * 8 + j, m = lane & 15, r = m & 3;
            int row = r * 40 + 4 * mt + (m >> 2);
            float s = (r == 3 ? SC2 : SC1);
            if (k < 40)       val = wcell[(l * 160 + row) * 40 + k] * s;
            else if (k == 40) val = bcell[l * 160 + row] * s;
        } else if (i < 80896) {                // conv a0
            int i3 = i - 71680;
            int j = i3 & 7, lane = (i3 >> 3) & 63, idx = i3 >> 9;   // 0..17
            int mtc = idx % 3, t2 = idx / 3, dx = t2 % 3, cv = t2 / 3;
            int k = (lane >> 4) * 8 + j;
            int ch = 16 * mtc + (lane & 15);
            const float* w = cv ? wrc : wrh;       // [40][40][1][3]
            if (ch < 40) val = w[(ch * 40 + k) * 3 + dx];
        } else if (i < 90112) {                // conv a1 ext
            int i4 = i - 80896;
            int j = i4 & 7, lane = (i4 >> 3) & 63, idx = i4 >> 9;
            int mtc = idx % 3, t2 = idx / 3, dx = t2 % 3, cv = t2 / 3;
            int k = 32 + (lane >> 4) * 8 + j;
            int ch = 16 * mtc + (lane & 15);
            if (ch < 40) {
                const float* w = cv ? wrc : wrh;
                if (k < 40)                    val = w[(ch * 40 + k) * 3 + dx];
                else if (k == 40 && dx == 1)   val = (cv ? brc : brh)[ch];
            }
        } else if (i < 105472) {               // F a0: A0·Wrh_dx, k=0..31
            int i5 = i - 90112;
            int j = i5 & 7, lane = (i5 >> 3) & 63, idx = i5 >> 9;   // 0..29
            int mt = idx % 10, dx = idx / 10;
            int k = (lane >> 4) * 8 + j, m = lane & 15, r = m & 3;
            int row = r * 40 + 4 * mt + (m >> 2);
            float s = (r == 3 ? SC2 : SC1);
            float acc = 0.0f;
            for (int mm = 0; mm < 40; mm++)
                acc = __builtin_fmaf(wcell[row * 40 + mm],
                                     wrh[(mm * 40 + k) * 3 + dx], acc);
            val = acc * s;
        } else if (i < 120832) {               // F a1 ext, k=32..47
            int i6 = i - 105472;
            int j = i6 & 7, lane = (i6 >> 3) & 63, idx = i6 >> 9;
            int mt = idx % 10, dx = idx / 10;
            int k = 32 + (lane >> 4) * 8 + j, m = lane & 15, r = m & 3;
            int row = r * 40 + 4 * mt + (m >> 2);
            float s = (r == 3 ? SC2 : SC1);
            if (k < 40) {
                float acc = 0.0f;
                for (int mm = 0; mm < 40; mm++)
                    acc = __builtin_fmaf(wcell[row * 40 + mm],
                                         wrh[(mm * 40 + k) * 3 + dx], acc);
                val = acc * s;
            } else if (k == 40 && dx == 1) {
                float acc = bcell[row];        // b_cell0 + A0·b_rh
                for (int mm = 0; mm < 40; mm++)
                    acc = __builtin_fmaf(wcell[row * 40 + mm], brh[mm], acc);
                val = acc * s;
            }
        } else if (i < 129024) {               // out a0: w_out, k=0..31
            int i7 = i - 120832;
            int j = i7 & 7, lane = (i7 >> 3) & 63, ot = i7 >> 9;    // 0..15
            int k = (lane >> 4) * 8 + j;
            int o = ot * 16 + (lane & 15);
            val = w_out[o * 40 + k];
        } else {                               // out a1x: k=32..47
            int i8 = i - 129024;
            int j = i8 & 7, lane = (i8 >> 3) & 63, ot = i8 >> 9;
            int k = 32 + (lane >> 4) * 8 + j;
            int o = ot * 16 + (lane & 15);
            if (k < 40)       val = w_out[o * 40 + k];
            else if (k == 40) val = b_out[o];
        }
        wsA[i] = (__bf16)val;
        return;
    }
    // ================= conv role: one (b, cc), whole plane =================
    const int b = bidx / 40, cc = bidx - b * 40;
    const int wv = tid >> 6, x = tid & 63;
    const int y0 = wv * 8;
    const float* ib = inp + b * 4096;
    const float* tb = tgt + b * 4096;
    const float* w0 = w_cis + cc * 49;
    const float* w1 = w_cis + (40 + cc) * 49;
    const float* w2 = w_is + cc * 49;
    const float* w3 = w_is + (40 + cc) * 49;
    const float bias0 = b_cis[cc], bias1 = b_cis[40 + cc];
    const float bias2 = b_is[cc],  bias3 = b_is[40 + cc];
    const int g = x >> 4, l16 = x & 15;
    const int jj = cc >> 2, qq = cc & 3;

    float pin[7][7], ptg[4][7];
    auto ldrow = [&](const float* base, int yy, float* dst) {
#pragma unroll
        for (int dx = 0; dx < 7; dx++) {
            int xx = x + dx - 3;
            bool ok = (yy >= 0 && yy < 64 && xx >= 0 && xx < 64);
            dst[dx] = ok ? base[yy * 64 + xx] : 0.0f;
        }
    };
    // prologue: inp rows y0-3..y0+3, tgt rows y0-3..y0
#pragma unroll
    for (int r = 0; r < 7; r++) ldrow(ib, y0 + r - 3, pin[r]);
#pragma unroll
    for (int r = 0; r < 4; r++) ldrow(tb, y0 + r - 3, ptg[r]);

#pragma unroll
    for (int iy = 0; iy < 8; iy++) {
        const int y = y0 + iy;
        if (iy > 0) {   // slide window down one row (renamed by full unroll)
#pragma unroll
            for (int r = 0; r < 6; r++)
#pragma unroll
                for (int dx = 0; dx < 7; dx++) pin[r][dx] = pin[r + 1][dx];
            ldrow(ib, y + 3, pin[6]);
#pragma unroll
            for (int r = 0; r < 3; r++)
#pragma unroll
                for (int dx = 0; dx < 7; dx++) ptg[r][dx] = ptg[r + 1][dx];
            ldrow(tb, y, ptg[3]);
        }
        float a0 = bias0, a1 = bias1, a2 = bias2, a3 = bias3;
#pragma unroll
        for (int dy = 0; dy < 7; dy++)
#pragma unroll
            for (int dx = 0; dx < 7; dx++) {
                a0 = __builtin_fmaf(w0[dy * 7 + dx], pin[dy][dx], a0);
                a1 = __builtin_fmaf(w1[dy * 7 + dx], pin[dy][dx], a1);
            }
#pragma unroll
        for (int dy = 0; dy < 3; dy++)
#pragma unroll
            for (int dx = 0; dx < 7; dx++) {
                a2 = __builtin_fmaf(w2[dy * 7 + dx], ptg[dy][dx], a2);
                a3 = __builtin_fmaf(w3[dy * 7 + dx], ptg[dy][dx], a3);
            }
#pragma unroll
        for (int dx = 0; dx < 3; dx++) {
            a2 = __builtin_fmaf(w2[21 + dx], ptg[3][dx], a2);
            a3 = __builtin_fmaf(w3[21 + dx], ptg[3][dx], a3);
        }
        size_t idx = (size_t)((((b * 64 + y) * 4 + g) * 10 + jj) * 4 + qq) * 64
                     + l16 * 4;
        *(f32x4*)&x_ws[idx] = f32x4{a0 * SC1, a1 * SC1, a2 * SC1, a3 * SC2};
    }
}

// ---------------------------------------------------------------------------
// rnn + dedicated out waves: 64 blocks x 768 threads (12 waves).
//  waves 0-9 : R8 cell structure verbatim (209us verified). No out work.
//  waves 10/11: out waves — window-0 of row t computes row t-1's out
//  (8 o-tiles each) from hC, then rides the barrier chain.
// halo_ws (u64): [bid][side2][parity2][ch40]; word = tag<<32 | c16<<16 | h16.
__global__ __launch_bounds__(768, 1) void rnn_kernel(
        const float* __restrict__ x_ws, const __bf16* __restrict__ wsA,
        unsigned long long* __restrict__ halo_ws, float* __restrict__ out) {
    // state, transposed [col 0..17][ch 0..47+pad]; col0/17 = halos; ch40 == 1.0
    __shared__ __align__(16) __bf16 hC[18 * STP + 64];
    __shared__ __align__(16) __bf16 cC[18 * STP + 64];
    __shared__ __align__(16) __bf16 hL[2 * HLS + 32];  // [buf][col][ch]
    __shared__ float cwf[40 * CWS];                    // conv c' fp32
    __shared__ unsigned cflag[4];                      // c' ready flags (tag=t)

    const int bid = blockIdx.x, g = bid >> 4, b = bid & 15;
    const int tid = threadIdx.x, wv = tid >> 6, lane = tid & 63;
    const int q = lane >> 4, l16 = lane & 15, cc = 4 * wv + q;
    const int W0 = g * 16;

    // ---- init LDS ----
    for (int i = tid; i < 536; i += 768) {   // 1072 bf16 = 536 floats
        ((float*)hC)[i] = 0.0f;
        ((float*)cC)[i] = 0.0f;
    }
    for (int i = tid; i < 912; i += 768)     // 1824 bf16 = 912 floats
        ((float*)hL)[i] = 0.0f;
    for (int i = tid; i < 40 * CWS; i += 768) cwf[i] = 0.0f;
    if (tid < 4) cflag[tid] = 0xFFFFFFFFu;
    __syncthreads();                          // zeros done BEFORE ones
    if (tid < 18) { hC[tid * STP + 40] = (__bf16)1.0f; cC[tid * STP + 40] = (__bf16)1.0f; }
    if (tid < 32) hL[(tid >> 4) * HLS + (tid & 15) * STP + 40] = (__bf16)1.0f;
    __syncthreads();

    // ---- preload fragments into registers ----
    bf16x8 a0c[6], a1c[6];                   // cell layers 1..6 (waves 0-9)
    bf16x8 f0c[3], f1c[3];                   // folded A0·Wrh_dx (layer 0)
    if (wv < 10) {
#pragma unroll
        for (int l = 1; l < 7; l++) {
            a0c[l - 1] = *(const bf16x8*)&wsA[((l * 10 + wv) * 64 + lane) * 8];
            a1c[l - 1] = *(const bf16x8*)&wsA[35840 + ((l * 10 + wv) * 64 + lane) * 8];
        }
#pragma unroll
        for (int dx = 0; dx < 3; dx++) {
            f0c[dx] = *(const bf16x8*)&wsA[90112 + ((dx * 10 + wv) * 64 + lane) * 8];
            f1c[dx] = *(const bf16x8*)&wsA[105472 + ((dx * 10 + wv) * 64 + lane) * 8];
        }
    }
    bf16x8 cva0[3], cva1[3];                 // Wrc conv (c' producers only)
    if (wv >= 3 && wv < 6) {
        int mtc = wv - 3;
#pragma unroll
        for (int dx = 0; dx < 3; dx++) {
            int it = (3 + dx) * 3 + mtc;     // cv=1 tiles
            cva0[dx] = *(const bf16x8*)&wsA[71680 + (it * 64 + lane) * 8];
            cva1[dx] = *(const bf16x8*)&wsA[80896 + (it * 64 + lane) * 8];
        }
    }
    bf16x8 o0c[8], o1c[8];                   // out waves: 8 tiles each
    if (wv >= 10) {
#pragma unroll
        for (int i = 0; i < 8; i++) {
            int ot = (wv - 10) * 8 + i;
            o0c[i] = *(const bf16x8*)&wsA[120832 + (ot * 64 + lane) * 8];
            o1c[i] = *(const bf16x8*)&wsA[129024 + (ot * 64 + lane) * 8];
        }
    }

    float c_reg = 0.0f;
    const size_t xstride = 10240;   // floats per (b,t)
    const size_t xbase0 = (size_t)(b * 64) * xstride
        + (((size_t)g * 10 + ((wv < 10) ? wv : 0)) * 4 + q) * 64 + l16 * 4;
    f32x4 xv = f32x4{0.f, 0.f, 0.f, 0.f};
    if (wv < 10) xv = *(const f32x4*)&x_ws[xbase0];   // row 0

    for (int t = 0; t < 64; t++) {
        // ---- prefetch x for row t+1 (cell waves only) ----
        f32x4 xn = xv;
        if (wv < 10 && t < 63)
            xn = *(const f32x4*)&x_ws[xbase0 + (size_t)(t + 1) * xstride];

        // ---- c' producers (waves 3-5): conv c, publish via flag ----
        if (wv >= 3 && wv < 6) {
            f32x4 ac = f32x4{0.f, 0.f, 0.f, 0.f};
#pragma unroll
            for (int dx = 0; dx < 3; dx++) {
                bf16x8 b0 = *(const bf16x8*)&cC[(l16 + dx) * STP + q * 8];
                bf16x8 b1 = *(const bf16x8*)&cC[(l16 + dx) * STP + 32 + q * 8];
                ac = __builtin_amdgcn_mfma_f32_16x16x32_bf16(cva0[dx], b0, ac, 0, 0, 0);
                ac = __builtin_amdgcn_mfma_f32_16x16x32_bf16(cva1[dx], b1, ac, 0, 0, 0);
            }
            int mtc = wv - 3, ch0 = 16 * mtc + 4 * q;
            if (ch0 < 40) {
#pragma unroll
                for (int r = 0; r < 4; r++) cwf[(ch0 + r) * CWS + l16] = ac[r];
            }
            __asm__ volatile("s_waitcnt lgkmcnt(0)" ::: "memory");
            if (lane == 0)
                __hip_atomic_store(&cflag[mtc], (unsigned)t,
                                   __ATOMIC_RELAXED, __HIP_MEMORY_SCOPE_WORKGROUP);
        }

        // ---- OUT waves (10/11): row t-1's output from hC, window-0 ----
        if (wv >= 10 && t > 0) {
            int y = t - 1;
            bf16x8 bo0 = *(const bf16x8*)&hC[(l16 + 1) * STP + q * 8];
            bf16x8 bo1 = *(const bf16x8*)&hC[(l16 + 1) * STP + 32 + q * 8];
#pragma unroll
            for (int i = 0; i < 8; i++) {
                f32x4 oa = __builtin_amdgcn_mfma_f32_16x16x32_bf16(
                    o0c[i], bo0, f32x4{0.f, 0.f, 0.f, 0.f}, 0, 0, 0);
                oa = __builtin_amdgcn_mfma_f32_16x16x32_bf16(o1c[i], bo1, oa, 0, 0, 0);
                int o0 = ((wv - 10) * 8 + i) * 16 + 4 * q;
#pragma unroll
                for (int r = 0; r < 4; r++)
                    out[((size_t)(b * 256 + o0 + r) * 64 + y) * 64 + W0 + l16] =
                        fmaxf(oa[r], 0.0f);
            }
        }

        // ---- layer-0 gate MFMAs + c'-wait (cell waves) ----
        f32x4 acc0 = f32x4{0.f, 0.f, 0.f, 0.f};
        if (wv < 10) {
#pragma unroll
            for (int dx = 0; dx < 3; dx++) {
                bf16x8 b0 = *(const bf16x8*)&hC[(l16 + dx) * STP + q * 8];
                bf16x8 b1 = *(const bf16x8*)&hC[(l16 + dx) * STP + 32 + q * 8];
                acc0 = __builtin_amdgcn_mfma_f32_16x16x32_bf16(f0c[dx], b0, acc0, 0, 0, 0);
                acc0 = __builtin_amdgcn_mfma_f32_16x16x32_bf16(f1c[dx], b1, acc0, 0, 0, 0);
            }
            int jj = wv >> 2;
            while (__hip_atomic_load(&cflag[jj], __ATOMIC_RELAXED,
                                     __HIP_MEMORY_SCOPE_WORKGROUP) != (unsigned)t)
                __builtin_amdgcn_s_sleep(1);
            __asm__ volatile("" ::: "memory");
        }

        // ---- 7 layers (barriers executed by ALL 12 waves) ----
#pragma unroll
        for (int l = 0; l < 7; l++) {
            if (wv < 10) {
                f32x4 acc;
                if (l == 0) {
                    acc = acc0;
                    c_reg = cwf[cc * CWS + l16];
                } else {
                    const __bf16* hb = &hL[(l & 1) * HLS];
                    bf16x8 b0 = *(const bf16x8*)&hb[l16 * STP + q * 8];
                    bf16x8 b1 = *(const bf16x8*)&hb[l16 * STP + 32 + q * 8];
                    acc = __builtin_amdgcn_mfma_f32_16x16x32_bf16(
                        a0c[l - 1], b0, f32x4{0.f, 0.f, 0.f, 0.f}, 0, 0, 0);
                    acc = __builtin_amdgcn_mfma_f32_16x16x32_bf16(a1c[l - 1], b1, acc, 0, 0, 0);
                }
                float Ei = __builtin_amdgcn_exp2f(fminf(acc[0] + xv[0], 44.f));
                float Ef = __builtin_amdgcn_exp2f(fminf(acc[1] + xv[1], 44.f));
                float Eo = __builtin_amdgcn_exp2f(fminf(acc[2] + xv[2], 44.f));
                float Eg = __builtin_amdgcn_exp2f(fminf(acc[3] + xv[3], 44.f));
                float f = __builtin_amdgcn_rcpf(1.0f + Ef);
                float ig = (1.0f - Eg) * __builtin_amdgcn_rcpf((1.0f + Ei) * (1.0f + Eg));
                float c = __builtin_fmaf(f, c_reg, ig);
                c_reg = c;
                float Ec = __builtin_amdgcn_exp2f(fminf(SC2 * c, 44.f));
                float h = (1.0f - Ec) * __builtin_amdgcn_rcpf((1.0f + Eo) * (1.0f + Ec));
                if (l < 6) {
                    hL[((l + 1) & 1) * HLS + l16 * STP + cc] = (__bf16)h;
                } else {
                    hC[(l16 + 1) * STP + cc] = (__bf16)h;
                    cC[(l16 + 1) * STP + cc] = (__bf16)c;
                    if (t < 63) {
                        unsigned short h16 = __builtin_bit_cast(unsigned short, (__bf16)h);
                        unsigned short c16 = __builtin_bit_cast(unsigned short, (__bf16)c);
                        unsigned long long v = ((unsigned long long)(unsigned)t << 32)
                            | ((unsigned)c16 << 16) | (unsigned)h16;
                        if (l16 == 0 && g > 0)
                            __hip_atomic_store(
                                &halo_ws[((bid * 2 + 0) * 2 + (t & 1)) * 40 + cc], v,
                                __ATOMIC_RELAXED, __HIP_MEMORY_SCOPE_AGENT);
                        if (l16 == 15 && g < 3)
                            __hip_atomic_store(
                                &halo_ws[((bid * 2 + 1) * 2 + (t & 1)) * 40 + cc], v,
                                __ATOMIC_RELAXED, __HIP_MEMORY_SCOPE_AGENT);
                    }
                }
            }
            if (l < 6) BARRIER_LGKM();
        }

        // ---- ingest neighbor halos for row t+1 (wv8: left, wv9: right) ----
        if (t < 63) {
            if (wv == 8 && g > 0 && lane < 40) {
                const unsigned long long* src =
                    &halo_ws[(((bid - 16) * 2 + 1) * 2 + (t & 1)) * 40 + lane];
                unsigned long long v = __hip_atomic_load(
                    src, __ATOMIC_RELAXED, __HIP_MEMORY_SCOPE_AGENT);
                while ((unsigned)(v >> 32) != (unsigned)t) {
                    __builtin_amdgcn_s_sleep(1);
                    v = __hip_atomic_load(src, __ATOMIC_RELAXED,
                                          __HIP_MEMORY_SCOPE_AGENT);
                }
                hC[lane] = __builtin_bit_cast(__bf16, (unsigned short)(v & 0xffffu));
                cC[lane] = __builtin_bit_cast(__bf16, (unsigned short)((v >> 16) & 0xffffu));
            }
            if (wv == 9 && g < 3 && lane < 40) {
                const unsigned long long* src =
                    &halo_ws[(((bid + 16) * 2 + 0) * 2 + (t & 1)) * 40 + lane];
                unsigned long long v = __hip_atomic_load(
                    src, __ATOMIC_RELAXED, __HIP_MEMORY_SCOPE_AGENT);
                while ((unsigned)(v >> 32) != (unsigned)t) {
                    __builtin_amdgcn_s_sleep(1);
                    v = __hip_atomic_load(src, __ATOMIC_RELAXED,
                                          __HIP_MEMORY_SCOPE_AGENT);
                }
                hC[17 * STP + lane] = __builtin_bit_cast(__bf16, (unsigned short)(v & 0xffffu));
                cC[17 * STP + lane] = __builtin_bit_cast(__bf16, (unsigned short)((v >> 16) & 0xffffu));
            }
        }
        BARRIER_LGKM();   // single end-of-row barrier (l6 writes + halo cols)
        xv = xn;
    }

    // ---- epilogue: OUT for row 63 (hC final state, post-barrier) ----
    if (wv >= 10) {
        bf16x8 bo0 = *(const bf16x8*)&hC[(l16 + 1) * STP + q * 8];
        bf16x8 bo1 = *(const bf16x8*)&hC[(l16 + 1) * STP + 32 + q * 8];
#pragma unroll
        for (int i = 0; i < 8; i++) {
            f32x4 oa = __builtin_amdgcn_mfma_f32_16x16x32_bf16(
                o0c[i], bo0, f32x4{0.f, 0.f, 0.f, 0.f}, 0, 0, 0);
            oa = __builtin_amdgcn_mfma_f32_16x16x32_bf16(o1c[i], bo1, oa, 0, 0, 0);
            int o0 = ((wv - 10) * 8 + i) * 16 + 4 * q;
#pragma unroll
            for (int r = 0; r < 4; r++)
                out[((size_t)(b * 256 + o0 + r) * 64 + 63) * 64 + W0 + l16] =
                    fmaxf(oa[r], 0.0f);
        }
    }
}

// ---------------------------------------------------------------------------
extern "C" void kernel_launch(void* const* d_in, const int* in_sizes, int n_in,
                              void* d_out, int out_size, void* d_ws,
                              size_t ws_size, hipStream_t stream) {
    const float* input  = (const float*)d_in[0];
    const float* target = (const float*)d_in[1];
    const float* w_is   = (const float*)d_in[2];
    const float* b_is   = (const float*)d_in[3];
    const float* w_cis  = (const float*)d_in[4];
    const float* b_cis  = (const float*)d_in[5];
    const float* w_rh   = (const float*)d_in[6];
    const float* b_rh   = (const float*)d_in[7];
    const float* w_rc   = (const float*)d_in[8];
    const float* b_rc   = (const float*)d_in[9];
    const float* w_cell = (const float*)d_in[10];
    const float* b_cell = (const float*)d_in[11];
    const float* w_out  = (const float*)d_in[12];
    const float* b_out  = (const float*)d_in[13];
    float* out = (float*)d_out;

    char* ws = (char*)d_ws;
    float*              x_ws    = (float*)ws;                        // 41,943,040 B
    __bf16*             wsA     = (__bf16*)(ws + 41943040);          //    274,432 B
    unsigned long long* halo_ws = (unsigned long long*)(ws + 42217472); // 81,920 B

    convprep_kernel<<<908, 512, 0, stream>>>(input, target, w_is, b_is,
                                             w_cis, b_cis, w_cell, w_rh,
                                             w_rc, b_cell, b_rh, b_rc,
                                             w_out, b_out, x_ws, wsA);
    rnn_kernel<<<64, 768, 0, stream>>>(x_ws, wsA, halo_ws, out);
}

// Round 13
// 626.154 us; speedup vs baseline: 1.1006x; 1.1006x over previous
//
#include <hip/hip_runtime.h>

// ---------------------------------------------------------------------------
// RowLSTM on MI355X — round 19: dedicated out waves, SPILL-PROOF register plan.
//  - R18 diagnosis: resident o0c[8]/o1c[8] (64 VGPR) on top of cell arrays
//    blew the per-kernel allocation (VGPR_Count pinned 84) -> scratch spill
//    (FETCH +6MB, WRITE +19MB, uniform 2.4x slowdown). The dedicated-wave
//    architecture was never actually tested.
//  - Fix: out waves (10/11) load each o-tile pair PER ROW PER TILE from wsA
//    (global; 32KB out-section is L2-resident -> FETCH_SIZE flat) with a
//    2-fragment transient live range. Out window-0 ~600-800cyc vs ~3300cyc
//    row -> one-time per-row offset, not cumulative (out waves sprint the
//    barrier chain after their work).
//  - Cell waves 0-9: byte-identical R8 structure (209us, verified x3).
// Carried: R16 channel-block conv + merged prep (2 dispatches), prefolded
// w_out/b_out tiles (bias via h[40]=1), R8 folded layer-0 + c' flag
// handshake, STP=56, packed 64-bit halo atomics, single end-of-row barrier,
// x double-buffer in regs, exp2-prescaled weights/x, lgkm-only barriers.
// ---------------------------------------------------------------------------

typedef __bf16 bf16x8 __attribute__((ext_vector_type(8)));
typedef __bf16 bf16x4 __attribute__((ext_vector_type(4)));
typedef float  f32x4  __attribute__((ext_vector_type(4)));

#define SC1 (-1.44269504089f)   // -log2(e)
#define SC2 (-2.88539008178f)   // -2 log2(e)

#define STP 56                   // bf16 elems per state column
#define HLS 896                  // hL per-buffer stride = 16*STP
#define CWS 17                   // cwf leading stride

#define BARRIER_LGKM() __asm__ volatile("s_waitcnt lgkmcnt(0)\ns_barrier" ::: "memory")

// ---------------------------------------------------------------------------
// Merged conv7 + prep dispatch: 908 blocks x 512 threads.
//  bid 0..639  : conv role, b = bid/40, cc = bid%40; wave wv rows 8wv..8wv+7.
//  bid 640..907: prep element i = (bid-640)*512+tid  (137216 total)
// wsA (bf16 elems):
//  [0     ,35840)  cell a0 : [(l*10+mt)][lane][j]  (l=0 part unused)
//  [35840 ,71680)  cell a1x: k<40 weight, k==40 bias, else 0
//  [71680 ,80896)  conv a0 : [(cv*9+dx*3+mtc)][lane][j] (cv=1 used)
//  [80896 ,90112)  conv a1x
//  [90112 ,105472) F a0  : F_dx = A0·Wrh_dx, scaled
//  [105472,120832) F a1x : k==40&&dx==1 -> s·(A0·b_rh + b_cell0)
//  [120832,129024) out a0 : [ot][lane][j]  o=ot*16+(lane&15), k=0..31, w_out
//  [129024,137216) out a1x: k=32..47; k<40 w_out, k==40 b_out, else 0
// x_ws (float, PRE-SCALED): [b][t][g4][mt10][q4][l16][gate4]
__global__ __launch_bounds__(512) void convprep_kernel(
        const float* __restrict__ inp, const float* __restrict__ tgt,
        const float* __restrict__ w_is, const float* __restrict__ b_is,
        const float* __restrict__ w_cis, const float* __restrict__ b_cis,
        const float* __restrict__ wcell, const float* __restrict__ wrh,
        const float* __restrict__ wrc, const float* __restrict__ bcell,
        const float* __restrict__ brh, const float* __restrict__ brc,
        const float* __restrict__ w_out, const float* __restrict__ b_out,
        float* __restrict__ x_ws, __bf16* __restrict__ wsA) {
    const int bidx = blockIdx.x;
    const int tid = threadIdx.x;
    if (bidx >= 640) {
        // ================= prep role =================
        int i = (bidx - 640) * 512 + tid;
        if (i >= 137216) return;
        float val = 0.0f;
        if (i < 35840) {                       // cell a0
            int j = i & 7, lane = (i >> 3) & 63, lm = i >> 9;
            int mt = lm % 10, l = lm / 10;
            int k = (lane >> 4) * 8 + j, m = lane & 15, r = m & 3;
            int row = r * 40 + 4 * mt + (m >> 2);
            val = wcell[(l * 160 + row) * 40 + k] * (r == 3 ? SC2 : SC1);
        } else if (i < 71680) {                // cell a1 ext
            int i2 = i - 35840;
            int j = i2 & 7, lane = (i2 >> 3) & 63, lm = i2 >> 9;
            int mt = lm % 10, l = lm / 10;
            int k = 32 + (lane >> 4) * 8 + j, m = lane & 15, r = m & 3;
            int row = r * 40 + 4 * mt + (m >> 2);
            float s = (r == 3 ? SC2 : SC1);
            if (k < 40)       val = wcell[(l * 160 + row) * 40 + k] * s;
            else if (k == 40) val = bcell[l * 160 + row] * s;
        } else if (i < 80896) {                // conv a0
            int i3 = i - 71680;
            int j = i3 & 7, lane = (i3 >> 3) & 63, idx = i3 >> 9;   // 0..17
            int mtc = idx % 3, t2 = idx / 3, dx = t2 % 3, cv = t2 / 3;
            int k = (lane >> 4) * 8 + j;
            int ch = 16 * mtc + (lane & 15);
            const float* w = cv ? wrc : wrh;       // [40][40][1][3]
            if (ch < 40) val = w[(ch * 40 + k) * 3 + dx];
        } else if (i < 90112) {                // conv a1 ext
            int i4 = i - 80896;
            int j = i4 & 7, lane = (i4 >> 3) & 63, idx = i4 >> 9;
            int mtc = idx % 3, t2 = idx / 3, dx = t2 % 3, cv = t2 / 3;
            int k = 32 + (lane >> 4) * 8 + j;
            int ch = 16 * mtc + (lane & 15);
            if (ch < 40) {
                const float* w = cv ? wrc : wrh;
                if (k < 40)                    val = w[(ch * 40 + k) * 3 + dx];
                else if (k == 40 && dx == 1)   val = (cv ? brc : brh)[ch];
            }
        } else if (i < 105472) {               // F a0: A0·Wrh_dx, k=0..31
            int i5 = i - 90112;
            int j = i5 & 7, lane = (i5 >> 3) & 63, idx = i5 >> 9;   // 0..29
            int mt = idx % 10, dx = idx / 10;
            int k = (lane >> 4) * 8 + j, m = lane & 15, r = m & 3;
            int row = r * 40 + 4 * mt + (m >> 2);
            float s = (r == 3 ? SC2 : SC1);
            float acc = 0.0f;
            for (int mm = 0; mm < 40; mm++)
                acc = __builtin_fmaf(wcell[row * 40 + mm],
                                     wrh[(mm * 40 + k) * 3 + dx], acc);
            val = acc * s;
        } else if (i < 120832) {               // F a1 ext, k=32..47
            int i6 = i - 105472;
            int j = i6 & 7, lane = (i6 >> 3) & 63, idx = i6 >> 9;
            int mt = idx % 10, dx = idx / 10;
            int k = 32 + (lane >> 4) * 8 + j, m = lane & 15, r = m & 3;
            int row = r * 40 + 4 * mt + (m >> 2);
            float s = (r == 3 ? SC2 : SC1);
            if (k < 40) {
                float acc = 0.0f;
                for (int mm = 0; mm < 40; mm++)
                    acc = __builtin_fmaf(wcell[row * 40 + mm],
                                         wrh[(mm * 40 + k) * 3 + dx], acc);
                val = acc * s;
            } else if (k == 40 && dx == 1) {
                float acc = bcell[row];        // b_cell0 + A0·b_rh
                for (int mm = 0; mm < 40; mm++)
                    acc = __builtin_fmaf(wcell[row * 40 + mm], brh[mm], acc);
                val = acc * s;
            }
        } else if (i < 129024) {               // out a0: w_out, k=0..31
            int i7 = i - 120832;
            int j = i7 & 7, lane = (i7 >> 3) & 63, ot = i7 >> 9;    // 0..15
            int k = (lane >> 4) * 8 + j;
            int o = ot * 16 + (lane & 15);
            val = w_out[o * 40 + k];
        } else {                               // out a1x: k=32..47
            int i8 = i - 129024;
            int j = i8 & 7, lane = (i8 >> 3) & 63, ot = i8 >> 9;
            int k = 32 + (lane >> 4) * 8 + j;
            int o = ot * 16 + (lane & 15);
            if (k < 40)       val = w_out[o * 40 + k];
            else if (k == 40) val = b_out[o];
        }
        wsA[i] = (__bf16)val;
        return;
    }
    // ================= conv role: one (b, cc), whole plane =================
    const int b = bidx / 40, cc = bidx - b * 40;
    const int wv = tid >> 6, x = tid & 63;
    const int y0 = wv * 8;
    const float* ib = inp + b * 4096;
    const float* tb = tgt + b * 4096;
    const float* w0 = w_cis + cc * 49;
    const float* w1 = w_cis + (40 + cc) * 49;
    const float* w2 = w_is + cc * 49;
    const float* w3 = w_is + (40 + cc) * 49;
    const float bias0 = b_cis[cc], bias1 = b_cis[40 + cc];
    const float bias2 = b_is[cc],  bias3 = b_is[40 + cc];
    const int g = x >> 4, l16 = x & 15;
    const int jj = cc >> 2, qq = cc & 3;

    float pin[7][7], ptg[4][7];
    auto ldrow = [&](const float* base, int yy, float* dst) {
#pragma unroll
        for (int dx = 0; dx < 7; dx++) {
            int xx = x + dx - 3;
            bool ok = (yy >= 0 && yy < 64 && xx >= 0 && xx < 64);
            dst[dx] = ok ? base[yy * 64 + xx] : 0.0f;
        }
    };
    // prologue: inp rows y0-3..y0+3, tgt rows y0-3..y0
#pragma unroll
    for (int r = 0; r < 7; r++) ldrow(ib, y0 + r - 3, pin[r]);
#pragma unroll
    for (int r = 0; r < 4; r++) ldrow(tb, y0 + r - 3, ptg[r]);

#pragma unroll
    for (int iy = 0; iy < 8; iy++) {
        const int y = y0 + iy;
        if (iy > 0) {   // slide window down one row (renamed by full unroll)
#pragma unroll
            for (int r = 0; r < 6; r++)
#pragma unroll
                for (int dx = 0; dx < 7; dx++) pin[r][dx] = pin[r + 1][dx];
            ldrow(ib, y + 3, pin[6]);
#pragma unroll
            for (int r = 0; r < 3; r++)
#pragma unroll
                for (int dx = 0; dx < 7; dx++) ptg[r][dx] = ptg[r + 1][dx];
            ldrow(tb, y, ptg[3]);
        }
        float a0 = bias0, a1 = bias1, a2 = bias2, a3 = bias3;
#pragma unroll
        for (int dy = 0; dy < 7; dy++)
#pragma unroll
            for (int dx = 0; dx < 7; dx++) {
                a0 = __builtin_fmaf(w0[dy * 7 + dx], pin[dy][dx], a0);
                a1 = __builtin_fmaf(w1[dy * 7 + dx], pin[dy][dx], a1);
            }
#pragma unroll
        for (int dy = 0; dy < 3; dy++)
#pragma unroll
            for (int dx = 0; dx < 7; dx++) {
                a2 = __builtin_fmaf(w2[dy * 7 + dx], ptg[dy][dx], a2);
                a3 = __builtin_fmaf(w3[dy * 7 + dx], ptg[dy][dx], a3);
            }
#pragma unroll
        for (int dx = 0; dx < 3; dx++) {
            a2 = __builtin_fmaf(w2[21 + dx], ptg[3][dx], a2);
            a3 = __builtin_fmaf(w3[21 + dx], ptg[3][dx], a3);
        }
        size_t idx = (size_t)((((b * 64 + y) * 4 + g) * 10 + jj) * 4 + qq) * 64
                     + l16 * 4;
        *(f32x4*)&x_ws[idx] = f32x4{a0 * SC1, a1 * SC1, a2 * SC1, a3 * SC2};
    }
}

// ---------------------------------------------------------------------------
// rnn + dedicated out waves: 64 blocks x 768 threads (12 waves).
//  waves 0-9 : R8 cell structure verbatim. No out work, no resident o-frags.
//  waves 10/11: out waves — per row, per tile, LOAD o-frags from wsA (L2)
//  with 2-frag transient live range, MFMA, store; then ride barrier chain.
// halo_ws (u64): [bid][side2][parity2][ch40]; word = tag<<32 | c16<<16 | h16.
__global__ __launch_bounds__(768, 1) void rnn_kernel(
        const float* __restrict__ x_ws, const __bf16* __restrict__ wsA,
        unsigned long long* __restrict__ halo_ws, float* __restrict__ out) {
    // state, transposed [col 0..17][ch 0..47+pad]; col0/17 = halos; ch40 == 1.0
    __shared__ __align__(16) __bf16 hC[18 * STP + 64];
    __shared__ __align__(16) __bf16 cC[18 * STP + 64];
    __shared__ __align__(16) __bf16 hL[2 * HLS + 32];  // [buf][col][ch]
    __shared__ float cwf[40 * CWS];                    // conv c' fp32
    __shared__ unsigned cflag[4];                      // c' ready flags (tag=t)

    const int bid = blockIdx.x, g = bid >> 4, b = bid & 15;
    const int tid = threadIdx.x, wv = tid >> 6, lane = tid & 63;
    const int q = lane >> 4, l16 = lane & 15, cc = 4 * wv + q;
    const int W0 = g * 16;

    // ---- init LDS ----
    for (int i = tid; i < 536; i += 768) {   // 1072 bf16 = 536 floats
        ((float*)hC)[i] = 0.0f;
        ((float*)cC)[i] = 0.0f;
    }
    for (int i = tid; i < 912; i += 768)     // 1824 bf16 = 912 floats
        ((float*)hL)[i] = 0.0f;
    for (int i = tid; i < 40 * CWS; i += 768) cwf[i] = 0.0f;
    if (tid < 4) cflag[tid] = 0xFFFFFFFFu;
    __syncthreads();                          // zeros done BEFORE ones
    if (tid < 18) { hC[tid * STP + 40] = (__bf16)1.0f; cC[tid * STP + 40] = (__bf16)1.0f; }
    if (tid < 32) hL[(tid >> 4) * HLS + (tid & 15) * STP + 40] = (__bf16)1.0f;
    __syncthreads();

    // ---- preload fragments into registers (cell waves only) ----
    bf16x8 a0c[6], a1c[6];                   // cell layers 1..6 (waves 0-9)
    bf16x8 f0c[3], f1c[3];                   // folded A0·Wrh_dx (layer 0)
    if (wv < 10) {
#pragma unroll
        for (int l = 1; l < 7; l++) {
            a0c[l - 1] = *(const bf16x8*)&wsA[((l * 10 + wv) * 64 + lane) * 8];
            a1c[l - 1] = *(const bf16x8*)&wsA[35840 + ((l * 10 + wv) * 64 + lane) * 8];
        }
#pragma unroll
        for (int dx = 0; dx < 3; dx++) {
            f0c[dx] = *(const bf16x8*)&wsA[90112 + ((dx * 10 + wv) * 64 + lane) * 8];
            f1c[dx] = *(const bf16x8*)&wsA[105472 + ((dx * 10 + wv) * 64 + lane) * 8];
        }
    }
    bf16x8 cva0[3], cva1[3];                 // Wrc conv (c' producers only)
    if (wv >= 3 && wv < 6) {
        int mtc = wv - 3;
#pragma unroll
        for (int dx = 0; dx < 3; dx++) {
            int it = (3 + dx) * 3 + mtc;     // cv=1 tiles
            cva0[dx] = *(const bf16x8*)&wsA[71680 + (it * 64 + lane) * 8];
            cva1[dx] = *(const bf16x8*)&wsA[80896 + (it * 64 + lane) * 8];
        }
    }
    // NOTE: out waves hold NO resident o-fragments (R18's spill). They load
    // per row per tile from wsA (L2-resident, 32KB section).

    float c_reg = 0.0f;
    const size_t xstride = 10240;   // floats per (b,t)
    const size_t xbase0 = (size_t)(b * 64) * xstride
        + (((size_t)g * 10 + ((wv < 10) ? wv : 0)) * 4 + q) * 64 + l16 * 4;
    f32x4 xv = f32x4{0.f, 0.f, 0.f, 0.f};
    if (wv < 10) xv = *(const f32x4*)&x_ws[xbase0];   // row 0

    for (int t = 0; t < 64; t++) {
        // ---- prefetch x for row t+1 (cell waves only) ----
        f32x4 xn = xv;
        if (wv < 10 && t < 63)
            xn = *(const f32x4*)&x_ws[xbase0 + (size_t)(t + 1) * xstride];

        // ---- c' producers (waves 3-5): conv c, publish via flag ----
        if (wv >= 3 && wv < 6) {
            f32x4 ac = f32x4{0.f, 0.f, 0.f, 0.f};
#pragma unroll
            for (int dx = 0; dx < 3; dx++) {
                bf16x8 b0 = *(const bf16x8*)&cC[(l16 + dx) * STP + q * 8];
                bf16x8 b1 = *(const bf16x8*)&cC[(l16 + dx) * STP + 32 + q * 8];
                ac = __builtin_amdgcn_mfma_f32_16x16x32_bf16(cva0[dx], b0, ac, 0, 0, 0);
                ac = __builtin_amdgcn_mfma_f32_16x16x32_bf16(cva1[dx], b1, ac, 0, 0, 0);
            }
            int mtc = wv - 3, ch0 = 16 * mtc + 4 * q;
            if (ch0 < 40) {
#pragma unroll
                for (int r = 0; r < 4; r++) cwf[(ch0 + r) * CWS + l16] = ac[r];
            }
            __asm__ volatile("s_waitcnt lgkmcnt(0)" ::: "memory");
            if (lane == 0)
                __hip_atomic_store(&cflag[mtc], (unsigned)t,
                                   __ATOMIC_RELAXED, __HIP_MEMORY_SCOPE_WORKGROUP);
        }

        // ---- OUT waves (10/11): row t-1's output, per-tile transient loads --
        if (wv >= 10 && t > 0) {
            int y = t - 1;
            bf16x8 bo0 = *(const bf16x8*)&hC[(l16 + 1) * STP + q * 8];
            bf16x8 bo1 = *(const bf16x8*)&hC[(l16 + 1) * STP + 32 + q * 8];
#pragma unroll
            for (int i = 0; i < 8; i++) {
                int ot = (wv - 10) * 8 + i;
                bf16x8 o0 = *(const bf16x8*)&wsA[120832 + (ot * 64 + lane) * 8];
                bf16x8 o1 = *(const bf16x8*)&wsA[129024 + (ot * 64 + lane) * 8];
                f32x4 oa = __builtin_amdgcn_mfma_f32_16x16x32_bf16(
                    o0, bo0, f32x4{0.f, 0.f, 0.f, 0.f}, 0, 0, 0);
                oa = __builtin_amdgcn_mfma_f32_16x16x32_bf16(o1, bo1, oa, 0, 0, 0);
                int o0i = ot * 16 + 4 * q;
#pragma unroll
                for (int r = 0; r < 4; r++)
                    out[((size_t)(b * 256 + o0i + r) * 64 + y) * 64 + W0 + l16] =
                        fmaxf(oa[r], 0.0f);
            }
        }

        // ---- layer-0 gate MFMAs + c'-wait (cell waves) ----
        f32x4 acc0 = f32x4{0.f, 0.f, 0.f, 0.f};
        if (wv < 10) {
#pragma unroll
            for (int dx = 0; dx < 3; dx++) {
                bf16x8 b0 = *(const bf16x8*)&hC[(l16 + dx) * STP + q * 8];
                bf16x8 b1 = *(const bf16x8*)&hC[(l16 + dx) * STP + 32 + q * 8];
                acc0 = __builtin_amdgcn_mfma_f32_16x16x32_bf16(f0c[dx], b0, acc0, 0, 0, 0);
                acc0 = __builtin_amdgcn_mfma_f32_16x16x32_bf16(f1c[dx], b1, acc0, 0, 0, 0);
            }
            int jj = wv >> 2;
            while (__hip_atomic_load(&cflag[jj], __ATOMIC_RELAXED,
                                     __HIP_MEMORY_SCOPE_WORKGROUP) != (unsigned)t)
                __builtin_amdgcn_s_sleep(1);
            __asm__ volatile("" ::: "memory");
        }

        // ---- 7 layers (barriers executed by ALL 12 waves) ----
#pragma unroll
        for (int l = 0; l < 7; l++) {
            if (wv < 10) {
                f32x4 acc;
                if (l == 0) {
                    acc = acc0;
                    c_reg = cwf[cc * CWS + l16];
                } else {
                    const __bf16* hb = &hL[(l & 1) * HLS];
                    bf16x8 b0 = *(const bf16x8*)&hb[l16 * STP + q * 8];
                    bf16x8 b1 = *(const bf16x8*)&hb[l16 * STP + 32 + q * 8];
                    acc = __builtin_amdgcn_mfma_f32_16x16x32_bf16(
                        a0c[l - 1], b0, f32x4{0.f, 0.f, 0.f, 0.f}, 0, 0, 0);
                    acc = __builtin_amdgcn_mfma_f32_16x16x32_bf16(a1c[l - 1], b1, acc, 0, 0, 0);
                }
                float Ei = __builtin_amdgcn_exp2f(fminf(acc[0] + xv[0], 44.f));
                float Ef = __builtin_amdgcn_exp2f(fminf(acc[1] + xv[1], 44.f));
                float Eo = __builtin_amdgcn_exp2f(fminf(acc[2] + xv[2], 44.f));
                float Eg = __builtin_amdgcn_exp2f(fminf(acc[3] + xv[3], 44.f));
                float f = __builtin_amdgcn_rcpf(1.0f + Ef);
                float ig = (1.0f - Eg) * __builtin_amdgcn_rcpf((1.0f + Ei) * (1.0f + Eg));
                float c = __builtin_fmaf(f, c_reg, ig);
                c_reg = c;
                float Ec = __builtin_amdgcn_exp2f(fminf(SC2 * c, 44.f));
                float h = (1.0f - Ec) * __builtin_amdgcn_rcpf((1.0f + Eo) * (1.0f + Ec));
                if (l < 6) {
                    hL[((l + 1) & 1) * HLS + l16 * STP + cc] = (__bf16)h;
                } else {
                    hC[(l16 + 1) * STP + cc] = (__bf16)h;
                    cC[(l16 + 1) * STP + cc] = (__bf16)c;
                    if (t < 63) {
                        unsigned short h16 = __builtin_bit_cast(unsigned short, (__bf16)h);
                        unsigned short c16 = __builtin_bit_cast(unsigned short, (__bf16)c);
                        unsigned long long v = ((unsigned long long)(unsigned)t << 32)
                            | ((unsigned)c16 << 16) | (unsigned)h16;
                        if (l16 == 0 && g > 0)
                            __hip_atomic_store(
                                &halo_ws[((bid * 2 + 0) * 2 + (t & 1)) * 40 + cc], v,
                                __ATOMIC_RELAXED, __HIP_MEMORY_SCOPE_AGENT);
                        if (l16 == 15 && g < 3)
                            __hip_atomic_store(
                                &halo_ws[((bid * 2 + 1) * 2 + (t & 1)) * 40 + cc], v,
                                __ATOMIC_RELAXED, __HIP_MEMORY_SCOPE_AGENT);
                    }
                }
            }
            if (l < 6) BARRIER_LGKM();
        }

        // ---- ingest neighbor halos for row t+1 (wv8: left, wv9: right) ----
        if (t < 63) {
            if (wv == 8 && g > 0 && lane < 40) {
                const unsigned long long* src =
                    &halo_ws[(((bid - 16) * 2 + 1) * 2 + (t & 1)) * 40 + lane];
                unsigned long long v = __hip_atomic_load(
                    src, __ATOMIC_RELAXED, __HIP_MEMORY_SCOPE_AGENT);
                while ((unsigned)(v >> 32) != (unsigned)t) {
                    __builtin_amdgcn_s_sleep(1);
                    v = __hip_atomic_load(src, __ATOMIC_RELAXED,
                                          __HIP_MEMORY_SCOPE_AGENT);
                }
                hC[lane] = __builtin_bit_cast(__bf16, (unsigned short)(v & 0xffffu));
                cC[lane] = __builtin_bit_cast(__bf16, (unsigned short)((v >> 16) & 0xffffu));
            }
            if (wv == 9 && g < 3 && lane < 40) {
                const unsigned long long* src =
                    &halo_ws[(((bid + 16) * 2 + 0) * 2 + (t & 1)) * 40 + lane];
                unsigned long long v = __hip_atomic_load(
                    src, __ATOMIC_RELAXED, __HIP_MEMORY_SCOPE_AGENT);
                while ((unsigned)(v >> 32) != (unsigned)t) {
                    __builtin_amdgcn_s_sleep(1);
                    v = __hip_atomic_load(src, __ATOMIC_RELAXED,
                                          __HIP_MEMORY_SCOPE_AGENT);
                }
                hC[17 * STP + lane] = __builtin_bit_cast(__bf16, (unsigned short)(v & 0xffffu));
                cC[17 * STP + lane] = __builtin_bit_cast(__bf16, (unsigned short)((v >> 16) & 0xffffu));
            }
        }
        BARRIER_LGKM();   // single end-of-row barrier (l6 writes + halo cols)
        xv = xn;
    }

    // ---- epilogue: OUT for row 63 (hC final state, post-barrier) ----
    if (wv >= 10) {
        bf16x8 bo0 = *(const bf16x8*)&hC[(l16 + 1) * STP + q * 8];
        bf16x8 bo1 = *(const bf16x8*)&hC[(l16 + 1) * STP + 32 + q * 8];
#pragma unroll
        for (int i = 0; i < 8; i++) {
            int ot = (wv - 10) * 8 + i;
            bf16x8 o0 = *(const bf16x8*)&wsA[120832 + (ot * 64 + lane) * 8];
            bf16x8 o1 = *(const bf16x8*)&wsA[129024 + (ot * 64 + lane) * 8];
            f32x4 oa = __builtin_amdgcn_mfma_f32_16x16x32_bf16(
                o0, bo0, f32x4{0.f, 0.f, 0.f, 0.f}, 0, 0, 0);
            oa = __builtin_amdgcn_mfma_f32_16x16x32_bf16(o1, bo1, oa, 0, 0, 0);
            int o0i = ot * 16 + 4 * q;
#pragma unroll
            for (int r = 0; r < 4; r++)
                out[((size_t)(b * 256 + o0i + r) * 64 + 63) * 64 + W0 + l16] =
                    fmaxf(oa[r], 0.0f);
        }
    }
}

// ---------------------------------------------------------------------------
extern "C" void kernel_launch(void* const* d_in, const int* in_sizes, int n_in,
                              void* d_out, int out_size, void* d_ws,
                              size_t ws_size, hipStream_t stream) {
    const float* input  = (const float*)d_in[0];
    const float* target = (const float*)d_in[1];
    const float* w_is   = (const float*)d_in[2];
    const float* b_is   = (const float*)d_in[3];
    const float* w_cis  = (const float*)d_in[4];
    const float* b_cis  = (const float*)d_in[5];
    const float* w_rh   = (const float*)d_in[6];
    const float* b_rh   = (const float*)d_in[7];
    const float* w_rc   = (const float*)d_in[8];
    const float* b_rc   = (const float*)d_in[9];
    const float* w_cell = (const float*)d_in[10];
    const float* b_cell = (const float*)d_in[11];
    const float* w_out  = (const float*)d_in[12];
    const float* b_out  = (const float*)d_in[13];
    float* out = (float*)d_out;

    char* ws = (char*)d_ws;
    float*              x_ws    = (float*)ws;                        // 41,943,040 B
    __bf16*             wsA     = (__bf16*)(ws + 41943040);          //    274,432 B
    unsigned long long* halo_ws = (unsigned long long*)(ws + 42217472); // 81,920 B

    convprep_kernel<<<908, 512, 0, stream>>>(input, target, w_is, b_is,
                                             w_cis, b_cis, w_cell, w_rh,
                                             w_rc, b_cell, b_rh, b_rc,
                                             w_out, b_out, x_ws, wsA);
    rnn_kernel<<<64, 768, 0, stream>>>(x_ws, wsA, halo_ws, out);
}

// Round 14
// 366.917 us; speedup vs baseline: 1.8781x; 1.7065x over previous
//
#include <hip/hip_runtime.h>

// ---------------------------------------------------------------------------
// RowLSTM on MI355X — round 20: restore best-measured config (R13, 366.3us).
//  - R18/R19 verdict: dedicated out waves spill at VGPR_Count=84 regardless
//    of transient-load plan (FETCH/WRITE inflation, ~2x stage stretch through
//    the shared barriers). Architecture abandoned.
//  - Ledger (measured): rnn-core 209 / 238 with out fold (best placement =
//    uniform waves 0-7 x2, R13, verified x3); out kernel separate = +26;
//    conv+prep = ~35; fixed overhead = ~95. All arrangements converge to
//    366-371. R13 = 366.3 is the best single measurement -> reproduced
//    verbatim: prep (536x256) + conv7 (1024x256, readfirstlane) + rnn
//    (64x640, out folded on waves 0-7, 2 tiles each, epilogue row 63).
// Carried: R8 folded layer-0 + c' flag handshake, STP=56, packed 64-bit halo
// atomics, single end-of-row barrier, x double-buffer in regs, exp2-prescaled
// weights/x, lgkm-only barriers, bias via constant channel h[40]=1.
// ---------------------------------------------------------------------------

typedef __bf16 bf16x8 __attribute__((ext_vector_type(8)));
typedef __bf16 bf16x4 __attribute__((ext_vector_type(4)));
typedef float  f32x4  __attribute__((ext_vector_type(4)));

#define SC1 (-1.44269504089f)   // -log2(e)
#define SC2 (-2.88539008178f)   // -2 log2(e)

#define STP 56                   // bf16 elems per state column
#define HLS 896                  // hL per-buffer stride = 16*STP
#define CWS 17                   // cwf leading stride

#define BARRIER_LGKM() __asm__ volatile("s_waitcnt lgkmcnt(0)\ns_barrier" ::: "memory")

// ---------------------------------------------------------------------------
// wsA (bf16 elems):
//  [0     ,35840)  cell a0 : [(l*10+mt)][lane][j]  (l=0 part unused)
//  [35840 ,71680)  cell a1x: k<40 weight, k==40 bias, else 0
//  [71680 ,80896)  conv a0 : [(cv*9+dx*3+mtc)][lane][j] (cv=1 used)
//  [80896 ,90112)  conv a1x
//  [90112 ,105472) F a0  : F_dx = A0·Wrh_dx, scaled
//  [105472,120832) F a1x : k==40&&dx==1 -> s·(A0·b_rh + b_cell0)
//  [120832,129024) out a0 : [ot][lane][j]  o=ot*16+(lane&15), k=0..31, w_out
//  [129024,137216) out a1x: k=32..47; k<40 w_out, k==40 b_out, else 0
__global__ __launch_bounds__(256) void prep_kernel(
        const float* __restrict__ wcell, const float* __restrict__ wrh,
        const float* __restrict__ wrc, const float* __restrict__ bcell,
        const float* __restrict__ brh, const float* __restrict__ brc,
        const float* __restrict__ w_out, const float* __restrict__ b_out,
        __bf16* __restrict__ wsA) {
    int i = blockIdx.x * 256 + threadIdx.x;
    if (i >= 137216) return;
    float val = 0.0f;
    if (i < 35840) {                       // cell a0
        int j = i & 7, lane = (i >> 3) & 63, lm = i >> 9;
        int mt = lm % 10, l = lm / 10;
        int k = (lane >> 4) * 8 + j, m = lane & 15, r = m & 3;
        int row = r * 40 + 4 * mt + (m >> 2);
        val = wcell[(l * 160 + row) * 40 + k] * (r == 3 ? SC2 : SC1);
    } else if (i < 71680) {                // cell a1 ext
        int i2 = i - 35840;
        int j = i2 & 7, lane = (i2 >> 3) & 63, lm = i2 >> 9;
        int mt = lm % 10, l = lm / 10;
        int k = 32 + (lane >> 4) * 8 + j, m = lane & 15, r = m & 3;
        int row = r * 40 + 4 * mt + (m >> 2);
        float s = (r == 3 ? SC2 : SC1);
        if (k < 40)       val = wcell[(l * 160 + row) * 40 + k] * s;
        else if (k == 40) val = bcell[l * 160 + row] * s;
    } else if (i < 80896) {                // conv a0
        int i3 = i - 71680;
        int j = i3 & 7, lane = (i3 >> 3) & 63, idx = i3 >> 9;   // 0..17
        int mtc = idx % 3, t2 = idx / 3, dx = t2 % 3, cv = t2 / 3;
        int k = (lane >> 4) * 8 + j;
        int ch = 16 * mtc + (lane & 15);
        const float* w = cv ? wrc : wrh;       // [40][40][1][3]
        if (ch < 40) val = w[(ch * 40 + k) * 3 + dx];
    } else if (i < 90112) {                // conv a1 ext
        int i4 = i - 80896;
        int j = i4 & 7, lane = (i4 >> 3) & 63, idx = i4 >> 9;
        int mtc = idx % 3, t2 = idx / 3, dx = t2 % 3, cv = t2 / 3;
        int k = 32 + (lane >> 4) * 8 + j;
        int ch = 16 * mtc + (lane & 15);
        if (ch < 40) {
            const float* w = cv ? wrc : wrh;
            if (k < 40)                    val = w[(ch * 40 + k) * 3 + dx];
            else if (k == 40 && dx == 1)   val = (cv ? brc : brh)[ch];
        }
    } else if (i < 105472) {               // F a0: A0·Wrh_dx, k=0..31
        int i5 = i - 90112;
        int j = i5 & 7, lane = (i5 >> 3) & 63, idx = i5 >> 9;   // 0..29
        int mt = idx % 10, dx = idx / 10;
        int k = (lane >> 4) * 8 + j, m = lane & 15, r = m & 3;
        int row = r * 40 + 4 * mt + (m >> 2);
        float s = (r == 3 ? SC2 : SC1);
        float acc = 0.0f;
        for (int mm = 0; mm < 40; mm++)
            acc = __builtin_fmaf(wcell[row * 40 + mm],
                                 wrh[(mm * 40 + k) * 3 + dx], acc);
        val = acc * s;
    } else if (i < 120832) {               // F a1 ext, k=32..47
        int i6 = i - 105472;
        int j = i6 & 7, lane = (i6 >> 3) & 63, idx = i6 >> 9;
        int mt = idx % 10, dx = idx / 10;
        int k = 32 + (lane >> 4) * 8 + j, m = lane & 15, r = m & 3;
        int row = r * 40 + 4 * mt + (m >> 2);
        float s = (r == 3 ? SC2 : SC1);
        if (k < 40) {
            float acc = 0.0f;
            for (int mm = 0; mm < 40; mm++)
                acc = __builtin_fmaf(wcell[row * 40 + mm],
                                     wrh[(mm * 40 + k) * 3 + dx], acc);
            val = acc * s;
        } else if (k == 40 && dx == 1) {
            float acc = bcell[row];        // b_cell0 + A0·b_rh
            for (int mm = 0; mm < 40; mm++)
                acc = __builtin_fmaf(wcell[row * 40 + mm], brh[mm], acc);
            val = acc * s;
        }
    } else if (i < 129024) {               // out a0: w_out, k=0..31
        int i7 = i - 120832;
        int j = i7 & 7, lane = (i7 >> 3) & 63, ot = i7 >> 9;    // 0..15
        int k = (lane >> 4) * 8 + j;
        int o = ot * 16 + (lane & 15);
        val = w_out[o * 40 + k];
    } else {                               // out a1x: k=32..47
        int i8 = i - 129024;
        int j = i8 & 7, lane = (i8 >> 3) & 63, ot = i8 >> 9;
        int k = 32 + (lane >> 4) * 8 + j;
        int o = ot * 16 + (lane & 15);
        if (k < 40)       val = w_out[o * 40 + k];
        else if (k == 40) val = b_out[o];
    }
    wsA[i] = (__bf16)val;
}

// ---------------------------------------------------------------------------
// x_ws (float, PRE-SCALED): [b][t][g4][mt10][q4][l16][gate4]
__global__ __launch_bounds__(256) void conv7_kernel(
        const float* __restrict__ inp, const float* __restrict__ tgt,
        const float* __restrict__ w_is, const float* __restrict__ b_is,
        const float* __restrict__ w_cis, const float* __restrict__ b_cis,
        float* __restrict__ x_ws) {
    int b = blockIdx.x >> 6, y = blockIdx.x & 63;
    int tid = threadIdx.x, qq = tid >> 6, w = tid & 63;
    const float* ib = inp + b * 4096;
    const float* tb = tgt + b * 4096;
    float pin[7][7], ptg[4][7];
#pragma unroll
    for (int dy = 0; dy < 7; dy++) {
        int yy = y + dy - 3;
#pragma unroll
        for (int dx = 0; dx < 7; dx++) {
            int xx = w + dx - 3;
            bool ok = (yy >= 0 && yy < 64 && xx >= 0 && xx < 64);
            pin[dy][dx] = ok ? ib[yy * 64 + xx] : 0.0f;
            if (dy < 4) ptg[dy][dx] = ok ? tb[yy * 64 + xx] : 0.0f;
        }
    }
    int g = w >> 4, l16 = w & 15;
    for (int j = 0; j < 10; j++) {
        int cc = 4 * j + qq;
        // cc is wave-uniform; readfirstlane makes loads provably uniform.
        int ccu = __builtin_amdgcn_readfirstlane(cc);
        float a0 = b_cis[ccu], a1 = b_cis[40 + ccu];
        float a2 = b_is[ccu], a3 = b_is[40 + ccu];
        const float* w0 = w_cis + ccu * 49;
        const float* w1 = w_cis + (40 + ccu) * 49;
        const float* w2 = w_is + ccu * 49;
        const float* w3 = w_is + (40 + ccu) * 49;
#pragma unroll
        for (int dy = 0; dy < 7; dy++)
#pragma unroll
            for (int dx = 0; dx < 7; dx++) {
                a0 = __builtin_fmaf(w0[dy * 7 + dx], pin[dy][dx], a0);
                a1 = __builtin_fmaf(w1[dy * 7 + dx], pin[dy][dx], a1);
            }
#pragma unroll
        for (int dy = 0; dy < 3; dy++)
#pragma unroll
            for (int dx = 0; dx < 7; dx++) {
                a2 = __builtin_fmaf(w2[dy * 7 + dx], ptg[dy][dx], a2);
                a3 = __builtin_fmaf(w3[dy * 7 + dx], ptg[dy][dx], a3);
            }
#pragma unroll
        for (int dx = 0; dx < 3; dx++) {
            a2 = __builtin_fmaf(w2[21 + dx], ptg[3][dx], a2);
            a3 = __builtin_fmaf(w3[21 + dx], ptg[3][dx], a3);
        }
        size_t idx = (size_t)((((b * 64 + y) * 4 + g) * 10 + j) * 4 + qq) * 64
                     + l16 * 4;
        *(f32x4*)&x_ws[idx] = f32x4{a0 * SC1, a1 * SC1, a2 * SC1, a3 * SC2};
    }
}

// ---------------------------------------------------------------------------
// rnn + fused out (R13-exact, measured 366.3 total): 64 blocks, bid = g*16+b.
// Out tiles: waves 0-7, 2 tiles each (uniform light spread — measured best).
// halo_ws (u64): [bid][side2][parity2][ch40]; word = tag<<32 | c16<<16 | h16.
__global__ __launch_bounds__(640, 1) void rnn_kernel(
        const float* __restrict__ x_ws, const __bf16* __restrict__ wsA,
        unsigned long long* __restrict__ halo_ws, float* __restrict__ out) {
    // state, transposed [col 0..17][ch 0..47+pad]; col0/17 = halos; ch40 == 1.0
    __shared__ __align__(16) __bf16 hC[18 * STP + 64];
    __shared__ __align__(16) __bf16 cC[18 * STP + 64];
    __shared__ __align__(16) __bf16 hL[2 * HLS + 32];  // [buf][col][ch]
    __shared__ float cwf[40 * CWS];                    // conv c' fp32
    __shared__ unsigned cflag[4];                      // c' ready flags (tag=t)

    const int bid = blockIdx.x, g = bid >> 4, b = bid & 15;
    const int tid = threadIdx.x, wv = tid >> 6, lane = tid & 63;
    const int q = lane >> 4, l16 = lane & 15, cc = 4 * wv + q;
    const int W0 = g * 16;

    // ---- init LDS ----
    for (int i = tid; i < 536; i += 640) {   // 1072 bf16 = 536 floats
        ((float*)hC)[i] = 0.0f;
        ((float*)cC)[i] = 0.0f;
    }
    for (int i = tid; i < 912; i += 640)     // 1824 bf16 = 912 floats
        ((float*)hL)[i] = 0.0f;
    for (int i = tid; i < 40 * CWS; i += 640) cwf[i] = 0.0f;
    if (tid < 4) cflag[tid] = 0xFFFFFFFFu;
    __syncthreads();                          // zeros done BEFORE ones
    if (tid < 18) { hC[tid * STP + 40] = (__bf16)1.0f; cC[tid * STP + 40] = (__bf16)1.0f; }
    if (tid < 32) hL[(tid >> 4) * HLS + (tid & 15) * STP + 40] = (__bf16)1.0f;
    __syncthreads();

    // ---- preload fragments into registers ----
    bf16x8 a0c[6], a1c[6];                   // cell layers 1..6 (index l-1)
#pragma unroll
    for (int l = 1; l < 7; l++) {
        a0c[l - 1] = *(const bf16x8*)&wsA[((l * 10 + wv) * 64 + lane) * 8];
        a1c[l - 1] = *(const bf16x8*)&wsA[35840 + ((l * 10 + wv) * 64 + lane) * 8];
    }
    bf16x8 f0c[3], f1c[3];                   // folded A0·Wrh_dx (layer 0)
#pragma unroll
    for (int dx = 0; dx < 3; dx++) {
        f0c[dx] = *(const bf16x8*)&wsA[90112 + ((dx * 10 + wv) * 64 + lane) * 8];
        f1c[dx] = *(const bf16x8*)&wsA[105472 + ((dx * 10 + wv) * 64 + lane) * 8];
    }
    bf16x8 cva0[3], cva1[3];                 // Wrc conv (c' producers only)
    if (wv >= 3 && wv < 6) {
        int mtc = wv - 3;
#pragma unroll
        for (int dx = 0; dx < 3; dx++) {
            int it = (3 + dx) * 3 + mtc;     // cv=1 tiles
            cva0[dx] = *(const bf16x8*)&wsA[71680 + (it * 64 + lane) * 8];
            cva1[dx] = *(const bf16x8*)&wsA[80896 + (it * 64 + lane) * 8];
        }
    }
    bf16x8 o0c[2], o1c[2];                   // w_out tiles (waves 0-7, 2 each)
    if (wv < 8) {
#pragma unroll
        for (int tt = 0; tt < 2; tt++) {
            int ot = 2 * wv + tt;
            o0c[tt] = *(const bf16x8*)&wsA[120832 + (ot * 64 + lane) * 8];
            o1c[tt] = *(const bf16x8*)&wsA[129024 + (ot * 64 + lane) * 8];
        }
    }

    float c_reg = 0.0f;
    const size_t xstride = 10240;   // floats per (b,t)
    const size_t xbase0 = (size_t)(b * 64) * xstride
        + (((size_t)g * 10 + wv) * 4 + q) * 64 + l16 * 4;
    f32x4 xv = *(const f32x4*)&x_ws[xbase0];   // row 0

    for (int t = 0; t < 64; t++) {
        // ---- prefetch x for row t+1 (held in regs, waited at first use) ----
        f32x4 xn = xv;
        if (t < 63) xn = *(const f32x4*)&x_ws[xbase0 + (size_t)(t + 1) * xstride];

        // ---- c' producers (waves 3-5): conv c, publish via flag ----
        if (wv >= 3 && wv < 6) {
            f32x4 ac = f32x4{0.f, 0.f, 0.f, 0.f};
#pragma unroll
            for (int dx = 0; dx < 3; dx++) {
                bf16x8 b0 = *(const bf16x8*)&cC[(l16 + dx) * STP + q * 8];
                bf16x8 b1 = *(const bf16x8*)&cC[(l16 + dx) * STP + 32 + q * 8];
                ac = __builtin_amdgcn_mfma_f32_16x16x32_bf16(cva0[dx], b0, ac, 0, 0, 0);
                ac = __builtin_amdgcn_mfma_f32_16x16x32_bf16(cva1[dx], b1, ac, 0, 0, 0);
            }
            int mtc = wv - 3, ch0 = 16 * mtc + 4 * q;
            if (ch0 < 40) {
#pragma unroll
                for (int r = 0; r < 4; r++) cwf[(ch0 + r) * CWS + l16] = ac[r];
            }
            __asm__ volatile("s_waitcnt lgkmcnt(0)" ::: "memory");
            if (lane == 0)
                __hip_atomic_store(&cflag[mtc], (unsigned)t,
                                   __ATOMIC_RELAXED, __HIP_MEMORY_SCOPE_WORKGROUP);
        }

        // ---- layer-0 gate MFMAs: folded conv+1x1 straight from hC ----
        f32x4 acc0 = f32x4{0.f, 0.f, 0.f, 0.f};
#pragma unroll
        for (int dx = 0; dx < 3; dx++) {
            bf16x8 b0 = *(const bf16x8*)&hC[(l16 + dx) * STP + q * 8];
            bf16x8 b1 = *(const bf16x8*)&hC[(l16 + dx) * STP + 32 + q * 8];
            acc0 = __builtin_amdgcn_mfma_f32_16x16x32_bf16(f0c[dx], b0, acc0, 0, 0, 0);
            acc0 = __builtin_amdgcn_mfma_f32_16x16x32_bf16(f1c[dx], b1, acc0, 0, 0, 0);
        }

        // ---- fused OUT for row t-1 (hC cols 1..16 still hold row t-1's h;
        //      the l0->l1 barrier below orders these reads vs l6 overwrite) ----
        if (t > 0 && wv < 8) {
            int y = t - 1;
            bf16x8 bo0 = *(const bf16x8*)&hC[(l16 + 1) * STP + q * 8];
            bf16x8 bo1 = *(const bf16x8*)&hC[(l16 + 1) * STP + 32 + q * 8];
#pragma unroll
            for (int tt = 0; tt < 2; tt++) {
                f32x4 oa = __builtin_amdgcn_mfma_f32_16x16x32_bf16(
                    o0c[tt], bo0, f32x4{0.f, 0.f, 0.f, 0.f}, 0, 0, 0);
                oa = __builtin_amdgcn_mfma_f32_16x16x32_bf16(o1c[tt], bo1, oa, 0, 0, 0);
                int o0 = (2 * wv + tt) * 16 + 4 * q;
#pragma unroll
                for (int r = 0; r < 4; r++)
                    out[((size_t)(b * 256 + o0 + r) * 64 + y) * 64 + W0 + l16] =
                        fmaxf(oa[r], 0.0f);
            }
        }

        // ---- wait for c' (usually 0 iterations) ----
        {
            int jj = wv >> 2;
            while (__hip_atomic_load(&cflag[jj], __ATOMIC_RELAXED,
                                     __HIP_MEMORY_SCOPE_WORKGROUP) != (unsigned)t)
                __builtin_amdgcn_s_sleep(1);
            __asm__ volatile("" ::: "memory");
        }

        // ---- 7 layers (l0 uses acc0; l1..6 read hL) ----
#pragma unroll
        for (int l = 0; l < 7; l++) {
            f32x4 acc;
            if (l == 0) {
                acc = acc0;
                c_reg = cwf[cc * CWS + l16];
            } else {
                const __bf16* hb = &hL[(l & 1) * HLS];
                bf16x8 b0 = *(const bf16x8*)&hb[l16 * STP + q * 8];
                bf16x8 b1 = *(const bf16x8*)&hb[l16 * STP + 32 + q * 8];
                acc = __builtin_amdgcn_mfma_f32_16x16x32_bf16(
                    a0c[l - 1], b0, f32x4{0.f, 0.f, 0.f, 0.f}, 0, 0, 0);
                acc = __builtin_amdgcn_mfma_f32_16x16x32_bf16(a1c[l - 1], b1, acc, 0, 0, 0);
            }
            float Ei = __builtin_amdgcn_exp2f(fminf(acc[0] + xv[0], 44.f));
            float Ef = __builtin_amdgcn_exp2f(fminf(acc[1] + xv[1], 44.f));
            float Eo = __builtin_amdgcn_exp2f(fminf(acc[2] + xv[2], 44.f));
            float Eg = __builtin_amdgcn_exp2f(fminf(acc[3] + xv[3], 44.f));
            float f = __builtin_amdgcn_rcpf(1.0f + Ef);
            float ig = (1.0f - Eg) * __builtin_amdgcn_rcpf((1.0f + Ei) * (1.0f + Eg));
            float c = __builtin_fmaf(f, c_reg, ig);
            c_reg = c;
            float Ec = __builtin_amdgcn_exp2f(fminf(SC2 * c, 44.f));
            float h = (1.0f - Ec) * __builtin_amdgcn_rcpf((1.0f + Eo) * (1.0f + Ec));
            if (l < 6) {
                hL[((l + 1) & 1) * HLS + l16 * STP + cc] = (__bf16)h;
                BARRIER_LGKM();
            } else {
                hC[(l16 + 1) * STP + cc] = (__bf16)h;
                cC[(l16 + 1) * STP + cc] = (__bf16)c;
                if (t < 63) {
                    unsigned short h16 = __builtin_bit_cast(unsigned short, (__bf16)h);
                    unsigned short c16 = __builtin_bit_cast(unsigned short, (__bf16)c);
                    unsigned long long v = ((unsigned long long)(unsigned)t << 32)
                        | ((unsigned)c16 << 16) | (unsigned)h16;
                    if (l16 == 0 && g > 0)
                        __hip_atomic_store(
                            &halo_ws[((bid * 2 + 0) * 2 + (t & 1)) * 40 + cc], v,
                            __ATOMIC_RELAXED, __HIP_MEMORY_SCOPE_AGENT);
                    if (l16 == 15 && g < 3)
                        __hip_atomic_store(
                            &halo_ws[((bid * 2 + 1) * 2 + (t & 1)) * 40 + cc], v,
                            __ATOMIC_RELAXED, __HIP_MEMORY_SCOPE_AGENT);
                }
                // no barrier here: merged with post-poll barrier below
            }
        }

        // ---- ingest neighbor halos for row t+1 (wv8: left, wv9: right) ----
        if (t < 63) {
            if (wv == 8 && g > 0 && lane < 40) {
                const unsigned long long* src =
                    &halo_ws[(((bid - 16) * 2 + 1) * 2 + (t & 1)) * 40 + lane];
                unsigned long long v = __hip_atomic_load(
                    src, __ATOMIC_RELAXED, __HIP_MEMORY_SCOPE_AGENT);
                while ((unsigned)(v >> 32) != (unsigned)t) {
                    __builtin_amdgcn_s_sleep(1);
                    v = __hip_atomic_load(src, __ATOMIC_RELAXED,
                                          __HIP_MEMORY_SCOPE_AGENT);
                }
                hC[lane] = __builtin_bit_cast(__bf16, (unsigned short)(v & 0xffffu));
                cC[lane] = __builtin_bit_cast(__bf16, (unsigned short)((v >> 16) & 0xffffu));
            }
            if (wv == 9 && g < 3 && lane < 40) {
                const unsigned long long* src =
                    &halo_ws[(((bid + 16) * 2 + 0) * 2 + (t & 1)) * 40 + lane];
                unsigned long long v = __hip_atomic_load(
                    src, __ATOMIC_RELAXED, __HIP_MEMORY_SCOPE_AGENT);
                while ((unsigned)(v >> 32) != (unsigned)t) {
                    __builtin_amdgcn_s_sleep(1);
                    v = __hip_atomic_load(src, __ATOMIC_RELAXED,
                                          __HIP_MEMORY_SCOPE_AGENT);
                }
                hC[17 * STP + lane] = __builtin_bit_cast(__bf16, (unsigned short)(v & 0xffffu));
                cC[17 * STP + lane] = __builtin_bit_cast(__bf16, (unsigned short)((v >> 16) & 0xffffu));
            }
        }
        BARRIER_LGKM();   // single end-of-row barrier (l6 writes + halo cols)
        xv = xn;
    }

    // ---- epilogue: OUT for row 63 (hC final state, post-barrier) ----
    if (wv < 8) {
        bf16x8 bo0 = *(const bf16x8*)&hC[(l16 + 1) * STP + q * 8];
        bf16x8 bo1 = *(const bf16x8*)&hC[(l16 + 1) * STP + 32 + q * 8];
#pragma unroll
        for (int tt = 0; tt < 2; tt++) {
            f32x4 oa = __builtin_amdgcn_mfma_f32_16x16x32_bf16(
                o0c[tt], bo0, f32x4{0.f, 0.f, 0.f, 0.f}, 0, 0, 0);
            oa = __builtin_amdgcn_mfma_f32_16x16x32_bf16(o1c[tt], bo1, oa, 0, 0, 0);
            int o0 = (2 * wv + tt) * 16 + 4 * q;
#pragma unroll
            for (int r = 0; r < 4; r++)
                out[((size_t)(b * 256 + o0 + r) * 64 + 63) * 64 + W0 + l16] =
                    fmaxf(oa[r], 0.0f);
        }
    }
}

// ---------------------------------------------------------------------------
extern "C" void kernel_launch(void* const* d_in, const int* in_sizes, int n_in,
                              void* d_out, int out_size, void* d_ws,
                              size_t ws_size, hipStream_t stream) {
    const float* input  = (const float*)d_in[0];
    const float* target = (const float*)d_in[1];
    const float* w_is   = (const float*)d_in[2];
    const float* b_is   = (const float*)d_in[3];
    const float* w_cis  = (const float*)d_in[4];
    const float* b_cis  = (const float*)d_in[5];
    const float* w_rh   = (const float*)d_in[6];
    const float* b_rh   = (const float*)d_in[7];
    const float* w_rc   = (const float*)d_in[8];
    const float* b_rc   = (const float*)d_in[9];
    const float* w_cell = (const float*)d_in[10];
    const float* b_cell = (const float*)d_in[11];
    const float* w_out  = (const float*)d_in[12];
    const float* b_out  = (const float*)d_in[13];
    float* out = (float*)d_out;

    char* ws = (char*)d_ws;
    float*              x_ws    = (float*)ws;                        // 41,943,040 B
    __bf16*             wsA     = (__bf16*)(ws + 41943040);          //    274,432 B
    unsigned long long* halo_ws = (unsigned long long*)(ws + 42217472); // 81,920 B

    prep_kernel<<<536, 256, 0, stream>>>(w_cell, w_rh, w_rc, b_cell, b_rh,
                                         b_rc, w_out, b_out, wsA);
    conv7_kernel<<<1024, 256, 0, stream>>>(input, target, w_is, b_is, w_cis,
                                           b_cis, x_ws);
    rnn_kernel<<<64, 640, 0, stream>>>(x_ws, wsA, halo_ws, out);
}